// Round 1
// baseline (712.119 us; speedup 1.0000x reference)
//
#include <hip/hip_runtime.h>
#include <hip/hip_bf16.h>
#include <math.h>

#define Bsz 4
#define CIN 128
#define LL 1024
#define DM 256
#define DI 512
#define DSTATE 64
#define DR 16
#define MM (Bsz * LL)   // 4096

__device__ __forceinline__ float silu_f(float x) {
    return x / (1.0f + __expf(-x));
}

// ---------------------------------------------------------------------------
// K1: x_seq[m][o] = sum_c x[b,c,l]*w_proj[o,c];  then LayerNorm -> xn
// block = 256 threads handles 4 pixels (m0..m0+3)
// ---------------------------------------------------------------------------
__global__ __launch_bounds__(256) void k_proj_ln(
    const float* __restrict__ x, const float* __restrict__ w_proj,
    const float* __restrict__ ln_g, const float* __restrict__ ln_b,
    float* __restrict__ x_seq, float* __restrict__ xn)
{
    __shared__ float xv[4][128];
    __shared__ float sSum[4][4], sSum2[4][4];
    __shared__ float sMean[4], sRstd[4];
    const int m0 = blockIdx.x * 4;
    const int b = m0 >> 10;
    const int l0 = m0 & 1023;
    const int tid = threadIdx.x;

    for (int idx = tid; idx < 512; idx += 256) {
        int c = idx >> 2, p = idx & 3;
        xv[p][c] = x[(b * CIN + c) * LL + l0 + p];
    }
    __syncthreads();

    const int o = tid;
    float acc[4] = {0.f, 0.f, 0.f, 0.f};
    const float4* wr = (const float4*)(w_proj + o * CIN);
#pragma unroll 8
    for (int i = 0; i < 32; i++) {
        float4 w4 = wr[i];
#pragma unroll
        for (int p = 0; p < 4; p++) {
            float4 x4 = ((const float4*)xv[p])[i];
            acc[p] = fmaf(w4.x, x4.x, acc[p]);
            acc[p] = fmaf(w4.y, x4.y, acc[p]);
            acc[p] = fmaf(w4.z, x4.z, acc[p]);
            acc[p] = fmaf(w4.w, x4.w, acc[p]);
        }
    }
    const int lane = tid & 63, wid = tid >> 6;
#pragma unroll
    for (int p = 0; p < 4; p++) {
        float v = acc[p], v2 = v * v;
#pragma unroll
        for (int off = 32; off; off >>= 1) {
            v  += __shfl_xor(v, off);
            v2 += __shfl_xor(v2, off);
        }
        if (lane == 0) { sSum[p][wid] = v; sSum2[p][wid] = v2; }
    }
    __syncthreads();
    if (tid < 4) {
        int p = tid;
        float s  = sSum[p][0] + sSum[p][1] + sSum[p][2] + sSum[p][3];
        float s2 = sSum2[p][0] + sSum2[p][1] + sSum2[p][2] + sSum2[p][3];
        float mean = s * (1.0f / 256.0f);
        float var  = s2 * (1.0f / 256.0f) - mean * mean;
        sMean[p] = mean;
        sRstd[p] = rsqrtf(var + 1e-5f);
    }
    __syncthreads();
    const float g = ln_g[o], bb = ln_b[o];
#pragma unroll
    for (int p = 0; p < 4; p++) {
        int m = m0 + p;
        x_seq[m * DM + o] = acc[p];
        xn[m * DM + o] = (acc[p] - sMean[p]) * sRstd[p] * g + bb;
    }
}

// ---------------------------------------------------------------------------
// Generic tiled GEMM: C[m][n] = sum_k A[m*lda+k] * W[n*ldw+k]
// 64x64 tile, 256 threads, K-tile 16, K % 16 == 0, M % 64 == 0, n guarded.
// LDS tiles stored transposed (k-major) -> conflict-free b128 compute reads.
// ---------------------------------------------------------------------------
__global__ __launch_bounds__(256) void k_gemm(
    const float* __restrict__ A, const float* __restrict__ W,
    float* __restrict__ C, int N, int K, int lda, int ldw, int ldc)
{
    __shared__ float As[16][64];
    __shared__ float Ws[16][64];
    const int tid = threadIdx.x;
    const int m0 = blockIdx.x * 64;
    const int n0 = blockIdx.y * 64;
    const int tm = tid & 15, tn = tid >> 4;
    const int row = tid >> 2, kq = tid & 3;
    float acc[4][4] = {};

    for (int k0 = 0; k0 < K; k0 += 16) {
        float4 a4 = *(const float4*)(A + (size_t)(m0 + row) * lda + k0 + kq * 4);
        As[kq * 4 + 0][row] = a4.x;
        As[kq * 4 + 1][row] = a4.y;
        As[kq * 4 + 2][row] = a4.z;
        As[kq * 4 + 3][row] = a4.w;
        int wn = n0 + row;
        float4 w4 = make_float4(0.f, 0.f, 0.f, 0.f);
        if (wn < N) w4 = *(const float4*)(W + (size_t)wn * ldw + k0 + kq * 4);
        Ws[kq * 4 + 0][row] = w4.x;
        Ws[kq * 4 + 1][row] = w4.y;
        Ws[kq * 4 + 2][row] = w4.z;
        Ws[kq * 4 + 3][row] = w4.w;
        __syncthreads();
#pragma unroll
        for (int k = 0; k < 16; k++) {
            float4 av = *(const float4*)&As[k][tm * 4];
            float4 wv = *(const float4*)&Ws[k][tn * 4];
            float a_[4] = {av.x, av.y, av.z, av.w};
            float w_[4] = {wv.x, wv.y, wv.z, wv.w};
#pragma unroll
            for (int i = 0; i < 4; i++)
#pragma unroll
                for (int j = 0; j < 4; j++)
                    acc[i][j] = fmaf(a_[i], w_[j], acc[i][j]);
        }
        __syncthreads();
    }
#pragma unroll
    for (int i = 0; i < 4; i++) {
        int m = m0 + tm * 4 + i;
#pragma unroll
        for (int j = 0; j < 4; j++) {
            int n = n0 + tn * 4 + j;
            if (n < N) C[(size_t)m * ldc + n] = acc[i][j];
        }
    }
}

// ---------------------------------------------------------------------------
// Depthwise causal conv (k=4) + bias + SiLU.
// u input = xz[:, :512] stored (m, 1024); output u_buf (m, 512)
// ---------------------------------------------------------------------------
__global__ __launch_bounds__(256) void k_conv_silu(
    const float* __restrict__ xz, const float* __restrict__ conv_w,
    const float* __restrict__ conv_b, float* __restrict__ u_buf)
{
    const int idx = blockIdx.x * 256 + threadIdx.x;   // b*2^19 + l*512 + d
    const int d = idx & 511;
    const int l = (idx >> 9) & 1023;
    const int b = idx >> 19;
    float acc = conv_b[d];
    const float* w = conv_w + d * 4;
#pragma unroll
    for (int j = 0; j < 4; j++) {
        int li = l - 3 + j;
        if (li >= 0)
            acc = fmaf(xz[(size_t)((b << 10) + li) * 1024 + d], w[j], acc);
    }
    u_buf[idx] = silu_f(acc);
}

// ---------------------------------------------------------------------------
// delta[m][n] = softplus( sum_r dt[m][r]*dtw[n][r] + dtb[n] ),  dt = x_dbl[:, :16]
// ---------------------------------------------------------------------------
__global__ __launch_bounds__(256) void k_delta(
    const float* __restrict__ x_dbl, const float* __restrict__ dtw,
    const float* __restrict__ dtb, float* __restrict__ delta)
{
    __shared__ float dtv[16];
    const int m = blockIdx.x;
    const int tid = threadIdx.x;
    if (tid < 16) dtv[tid] = x_dbl[(size_t)m * 144 + tid];
    __syncthreads();
#pragma unroll
    for (int nn = 0; nn < 2; nn++) {
        int n = tid + nn * 256;
        float acc = dtb[n];
        const float4* wr = (const float4*)(dtw + n * 16);
#pragma unroll
        for (int r4 = 0; r4 < 4; r4++) {
            float4 w4 = wr[r4];
            float4 d4 = ((const float4*)dtv)[r4];
            acc = fmaf(w4.x, d4.x, acc);
            acc = fmaf(w4.y, d4.y, acc);
            acc = fmaf(w4.z, d4.z, acc);
            acc = fmaf(w4.w, d4.w, acc);
        }
        delta[(size_t)m * DI + n] = (acc > 20.0f) ? acc : log1pf(__expf(acc));
    }
}

// ---------------------------------------------------------------------------
// Selective scan: one wave per (b,d); lane = s (d_state=64).
// h_t = exp(delta*A)*h + delta*u*B_t ; y_t = <h, C_t> + u*D
// ---------------------------------------------------------------------------
__global__ __launch_bounds__(256) void k_scan(
    const float* __restrict__ delta, const float* __restrict__ u_buf,
    const float* __restrict__ x_dbl, const float* __restrict__ A_log,
    const float* __restrict__ Dp, float* __restrict__ y_buf)
{
    const int wid = (blockIdx.x << 2) + (threadIdx.x >> 6);  // 0..2047
    const int b = wid >> 9;
    const int d = wid & 511;
    const int s = threadIdx.x & 63;
    const float A = -__expf(A_log[d * DSTATE + s]);
    const float Dd = Dp[d];
    const float* dl = delta + (size_t)(b << 10) * DI + d;
    const float* uu = u_buf + (size_t)(b << 10) * DI + d;
    const float* xd = x_dbl + (size_t)(b << 10) * 144;
    float* yo = y_buf + (size_t)(b << 10) * DI + d;
    float h = 0.f;
    for (int t = 0; t < 1024; t++) {
        float dt_ = dl[(size_t)t * DI];
        float ut  = uu[(size_t)t * DI];
        float Bv  = xd[(size_t)t * 144 + 16 + s];
        float Cv  = xd[(size_t)t * 144 + 80 + s];
        float dA = __expf(dt_ * A);
        h = fmaf(dA, h, dt_ * ut * Bv);
        float p = h * Cv;
#pragma unroll
        for (int off = 32; off; off >>= 1) p += __shfl_xor(p, off);
        if (s == 0) yo[(size_t)t * DI] = fmaf(ut, Dd, p);
    }
}

// ---------------------------------------------------------------------------
// Out GEMM: A[m][k] = y[m][k]*silu(z[m][k]); C = A @ out_proj_w^T + x_seq,
// stored NCHW: out[(b*256+n)*1024 + l].  K=512, N=256.
// ---------------------------------------------------------------------------
__global__ __launch_bounds__(256) void k_gemm_out(
    const float* __restrict__ Y, const float* __restrict__ XZ,
    const float* __restrict__ W, const float* __restrict__ x_seq,
    float* __restrict__ out)
{
    __shared__ float As[16][64];
    __shared__ float Ws[16][64];
    const int tid = threadIdx.x;
    const int m0 = blockIdx.x * 64;
    const int n0 = blockIdx.y * 64;
    const int tm = tid & 15, tn = tid >> 4;
    const int row = tid >> 2, kq = tid & 3;
    float acc[4][4] = {};

    for (int k0 = 0; k0 < 512; k0 += 16) {
        float4 y4 = *(const float4*)(Y + (size_t)(m0 + row) * DI + k0 + kq * 4);
        float4 z4 = *(const float4*)(XZ + (size_t)(m0 + row) * 1024 + 512 + k0 + kq * 4);
        As[kq * 4 + 0][row] = y4.x * silu_f(z4.x);
        As[kq * 4 + 1][row] = y4.y * silu_f(z4.y);
        As[kq * 4 + 2][row] = y4.z * silu_f(z4.z);
        As[kq * 4 + 3][row] = y4.w * silu_f(z4.w);
        float4 w4 = *(const float4*)(W + (size_t)(n0 + row) * DI + k0 + kq * 4);
        Ws[kq * 4 + 0][row] = w4.x;
        Ws[kq * 4 + 1][row] = w4.y;
        Ws[kq * 4 + 2][row] = w4.z;
        Ws[kq * 4 + 3][row] = w4.w;
        __syncthreads();
#pragma unroll
        for (int k = 0; k < 16; k++) {
            float4 av = *(const float4*)&As[k][tm * 4];
            float4 wv = *(const float4*)&Ws[k][tn * 4];
            float a_[4] = {av.x, av.y, av.z, av.w};
            float w_[4] = {wv.x, wv.y, wv.z, wv.w};
#pragma unroll
            for (int i = 0; i < 4; i++)
#pragma unroll
                for (int j = 0; j < 4; j++)
                    acc[i][j] = fmaf(a_[i], w_[j], acc[i][j]);
        }
        __syncthreads();
    }

    const int b = m0 >> 10;
    const int l0 = (m0 & 1023) + tm * 4;
#pragma unroll
    for (int j = 0; j < 4; j++) {
        int n = n0 + tn * 4 + j;
        float r0 = acc[0][j] + x_seq[(size_t)(m0 + tm * 4 + 0) * DM + n];
        float r1 = acc[1][j] + x_seq[(size_t)(m0 + tm * 4 + 1) * DM + n];
        float r2 = acc[2][j] + x_seq[(size_t)(m0 + tm * 4 + 2) * DM + n];
        float r3 = acc[3][j] + x_seq[(size_t)(m0 + tm * 4 + 3) * DM + n];
        *(float4*)(out + (size_t)(b * DM + n) * LL + l0) = make_float4(r0, r1, r2, r3);
    }
}

extern "C" void kernel_launch(void* const* d_in, const int* in_sizes, int n_in,
                              void* d_out, int out_size, void* d_ws, size_t ws_size,
                              hipStream_t stream)
{
    const float* x         = (const float*)d_in[0];
    const float* w_proj    = (const float*)d_in[1];
    const float* ln_g      = (const float*)d_in[2];
    const float* ln_b      = (const float*)d_in[3];
    const float* in_proj_w = (const float*)d_in[4];
    const float* conv_w    = (const float*)d_in[5];
    const float* conv_b    = (const float*)d_in[6];
    const float* x_proj_w  = (const float*)d_in[7];
    const float* dt_proj_w = (const float*)d_in[8];
    const float* dt_proj_b = (const float*)d_in[9];
    const float* A_log     = (const float*)d_in[10];
    const float* Dp        = (const float*)d_in[11];
    const float* out_proj_w= (const float*)d_in[12];
    float* out = (float*)d_out;

    float* ws    = (float*)d_ws;
    float* x_seq = ws;                     // 4096*256   = 1,048,576
    float* xn    = ws + 1 * 1048576;       // 4096*256
    float* xz    = ws + 2 * 1048576;       // 4096*1024  = 4,194,304
    float* u_buf = ws + 6 * 1048576;       // 4096*512   = 2,097,152
    float* x_dbl = ws + 8 * 1048576;       // 4096*144   =   589,824
    float* delta = ws + 9 * 1048576;       // 4096*512
    float* y_buf = ws + 11 * 1048576;      // 4096*512

    // 1. projection + layernorm
    k_proj_ln<<<dim3(MM / 4), dim3(256), 0, stream>>>(x, w_proj, ln_g, ln_b, x_seq, xn);
    // 2. in_proj: xn(4096x256) @ in_proj_w^T(256x1024) -> xz
    k_gemm<<<dim3(MM / 64, 1024 / 64), dim3(256), 0, stream>>>(
        xn, in_proj_w, xz, 1024, 256, 256, 256, 1024);
    // 3. depthwise conv + silu -> u_buf
    k_conv_silu<<<dim3(Bsz * LL * DI / 256), dim3(256), 0, stream>>>(xz, conv_w, conv_b, u_buf);
    // 4. x_proj: u(4096x512) @ x_proj_w^T(512x144) -> x_dbl
    k_gemm<<<dim3(MM / 64, 3), dim3(256), 0, stream>>>(
        u_buf, x_proj_w, x_dbl, 144, 512, 512, 512, 144);
    // 5. dt_proj + softplus -> delta
    k_delta<<<dim3(MM), dim3(256), 0, stream>>>(x_dbl, dt_proj_w, dt_proj_b, delta);
    // 6. selective scan -> y_buf
    k_scan<<<dim3(512), dim3(256), 0, stream>>>(delta, u_buf, x_dbl, A_log, Dp, y_buf);
    // 7. gated out_proj + residual, NCHW store
    k_gemm_out<<<dim3(MM / 64, 256 / 64), dim3(256), 0, stream>>>(
        y_buf, xz, out_proj_w, x_seq, out);
}

// Round 2
// 299.706 us; speedup vs baseline: 2.3761x; 2.3761x over previous
//
#include <hip/hip_runtime.h>
#include <hip/hip_bf16.h>
#include <math.h>

#define Bsz 4
#define CIN 128
#define LL 1024
#define DM 256
#define DI 512
#define DSTATE 64
#define DR 16
#define MM (Bsz * LL)   // 4096
#define NC 16           // scan chunks
#define CL 64           // chunk length (LL/NC)

__device__ __forceinline__ float silu_f(float x) {
    return x / (1.0f + __expf(-x));
}

// ---------------------------------------------------------------------------
// K1: x_seq[m][o] = sum_c x[b,c,l]*w_proj[o,c];  then LayerNorm -> xn
// ---------------------------------------------------------------------------
__global__ __launch_bounds__(256) void k_proj_ln(
    const float* __restrict__ x, const float* __restrict__ w_proj,
    const float* __restrict__ ln_g, const float* __restrict__ ln_b,
    float* __restrict__ x_seq, float* __restrict__ xn)
{
    __shared__ float xv[4][128];
    __shared__ float sSum[4][4], sSum2[4][4];
    __shared__ float sMean[4], sRstd[4];
    const int m0 = blockIdx.x * 4;
    const int b = m0 >> 10;
    const int l0 = m0 & 1023;
    const int tid = threadIdx.x;

    for (int idx = tid; idx < 512; idx += 256) {
        int c = idx >> 2, p = idx & 3;
        xv[p][c] = x[(b * CIN + c) * LL + l0 + p];
    }
    __syncthreads();

    const int o = tid;
    float acc[4] = {0.f, 0.f, 0.f, 0.f};
    const float4* wr = (const float4*)(w_proj + o * CIN);
#pragma unroll 8
    for (int i = 0; i < 32; i++) {
        float4 w4 = wr[i];
#pragma unroll
        for (int p = 0; p < 4; p++) {
            float4 x4 = ((const float4*)xv[p])[i];
            acc[p] = fmaf(w4.x, x4.x, acc[p]);
            acc[p] = fmaf(w4.y, x4.y, acc[p]);
            acc[p] = fmaf(w4.z, x4.z, acc[p]);
            acc[p] = fmaf(w4.w, x4.w, acc[p]);
        }
    }
    const int lane = tid & 63, wid = tid >> 6;
#pragma unroll
    for (int p = 0; p < 4; p++) {
        float v = acc[p], v2 = v * v;
#pragma unroll
        for (int off = 32; off; off >>= 1) {
            v  += __shfl_xor(v, off);
            v2 += __shfl_xor(v2, off);
        }
        if (lane == 0) { sSum[p][wid] = v; sSum2[p][wid] = v2; }
    }
    __syncthreads();
    if (tid < 4) {
        int p = tid;
        float s  = sSum[p][0] + sSum[p][1] + sSum[p][2] + sSum[p][3];
        float s2 = sSum2[p][0] + sSum2[p][1] + sSum2[p][2] + sSum2[p][3];
        float mean = s * (1.0f / 256.0f);
        float var  = s2 * (1.0f / 256.0f) - mean * mean;
        sMean[p] = mean;
        sRstd[p] = rsqrtf(var + 1e-5f);
    }
    __syncthreads();
    const float g = ln_g[o], bb = ln_b[o];
#pragma unroll
    for (int p = 0; p < 4; p++) {
        int m = m0 + p;
        x_seq[m * DM + o] = acc[p];
        xn[m * DM + o] = (acc[p] - sMean[p]) * sRstd[p] * g + bb;
    }
}

// ---------------------------------------------------------------------------
// Generic tiled GEMM: C[m][n] = sum_k A[m*lda+k] * W[n*ldw+k]
// ---------------------------------------------------------------------------
__global__ __launch_bounds__(256) void k_gemm(
    const float* __restrict__ A, const float* __restrict__ W,
    float* __restrict__ C, int N, int K, int lda, int ldw, int ldc)
{
    __shared__ float As[16][64];
    __shared__ float Ws[16][64];
    const int tid = threadIdx.x;
    const int m0 = blockIdx.x * 64;
    const int n0 = blockIdx.y * 64;
    const int tm = tid & 15, tn = tid >> 4;
    const int row = tid >> 2, kq = tid & 3;
    float acc[4][4] = {};

    for (int k0 = 0; k0 < K; k0 += 16) {
        float4 a4 = *(const float4*)(A + (size_t)(m0 + row) * lda + k0 + kq * 4);
        As[kq * 4 + 0][row] = a4.x;
        As[kq * 4 + 1][row] = a4.y;
        As[kq * 4 + 2][row] = a4.z;
        As[kq * 4 + 3][row] = a4.w;
        int wn = n0 + row;
        float4 w4 = make_float4(0.f, 0.f, 0.f, 0.f);
        if (wn < N) w4 = *(const float4*)(W + (size_t)wn * ldw + k0 + kq * 4);
        Ws[kq * 4 + 0][row] = w4.x;
        Ws[kq * 4 + 1][row] = w4.y;
        Ws[kq * 4 + 2][row] = w4.z;
        Ws[kq * 4 + 3][row] = w4.w;
        __syncthreads();
#pragma unroll
        for (int k = 0; k < 16; k++) {
            float4 av = *(const float4*)&As[k][tm * 4];
            float4 wv = *(const float4*)&Ws[k][tn * 4];
            float a_[4] = {av.x, av.y, av.z, av.w};
            float w_[4] = {wv.x, wv.y, wv.z, wv.w};
#pragma unroll
            for (int i = 0; i < 4; i++)
#pragma unroll
                for (int j = 0; j < 4; j++)
                    acc[i][j] = fmaf(a_[i], w_[j], acc[i][j]);
        }
        __syncthreads();
    }
#pragma unroll
    for (int i = 0; i < 4; i++) {
        int m = m0 + tm * 4 + i;
#pragma unroll
        for (int j = 0; j < 4; j++) {
            int n = n0 + tn * 4 + j;
            if (n < N) C[(size_t)m * ldc + n] = acc[i][j];
        }
    }
}

// ---------------------------------------------------------------------------
// Depthwise causal conv (k=4) + bias + SiLU.
// ---------------------------------------------------------------------------
__global__ __launch_bounds__(256) void k_conv_silu(
    const float* __restrict__ xz, const float* __restrict__ conv_w,
    const float* __restrict__ conv_b, float* __restrict__ u_buf)
{
    const int idx = blockIdx.x * 256 + threadIdx.x;   // b*2^19 + l*512 + d
    const int d = idx & 511;
    const int l = (idx >> 9) & 1023;
    const int b = idx >> 19;
    float acc = conv_b[d];
    const float* w = conv_w + d * 4;
#pragma unroll
    for (int j = 0; j < 4; j++) {
        int li = l - 3 + j;
        if (li >= 0)
            acc = fmaf(xz[(size_t)((b << 10) + li) * 1024 + d], w[j], acc);
    }
    u_buf[idx] = silu_f(acc);
}

// ---------------------------------------------------------------------------
// delta = softplus(dt @ dt_proj_w^T + dt_proj_b)
// ---------------------------------------------------------------------------
__global__ __launch_bounds__(256) void k_delta(
    const float* __restrict__ x_dbl, const float* __restrict__ dtw,
    const float* __restrict__ dtb, float* __restrict__ delta)
{
    __shared__ float dtv[16];
    const int m = blockIdx.x;
    const int tid = threadIdx.x;
    if (tid < 16) dtv[tid] = x_dbl[(size_t)m * 144 + tid];
    __syncthreads();
#pragma unroll
    for (int nn = 0; nn < 2; nn++) {
        int n = tid + nn * 256;
        float acc = dtb[n];
        const float4* wr = (const float4*)(dtw + n * 16);
#pragma unroll
        for (int r4 = 0; r4 < 4; r4++) {
            float4 w4 = wr[r4];
            float4 d4 = ((const float4*)dtv)[r4];
            acc = fmaf(w4.x, d4.x, acc);
            acc = fmaf(w4.y, d4.y, acc);
            acc = fmaf(w4.z, d4.z, acc);
            acc = fmaf(w4.w, d4.w, acc);
        }
        delta[(size_t)m * DI + n] = (acc > 20.0f) ? acc : log1pf(__expf(acc));
    }
}

// ---------------------------------------------------------------------------
// Chunked selective scan.
// Wave layout: 4 groups of 16 lanes; group g -> d = d0+g; lane j in group
// holds states s = 4j..4j+3.  Wave id -> (b, d0, chunk c).
// Pass 1: local recurrence from h=0; store h_end[4] and decay prod[4]
//   at hend/decay[((c*2048 + b*512 + d) * 64) + s]  (coalesced float4).
// ---------------------------------------------------------------------------
__global__ __launch_bounds__(256) void k_scan_p1(
    const float* __restrict__ delta, const float* __restrict__ u_buf,
    const float* __restrict__ x_dbl, const float* __restrict__ A_log,
    float* __restrict__ hend, float* __restrict__ decay)
{
    const int wid = (blockIdx.x << 2) + (threadIdx.x >> 6);  // 0..8191
    const int lane = threadIdx.x & 63;
    const int g = lane >> 4, j = lane & 15;
    const int d = ((wid & 127) << 2) + g;
    const int c = (wid >> 7) & 15;
    const int b = wid >> 11;
    float4 Al = *(const float4*)(A_log + d * DSTATE + j * 4);
    const float A0 = -__expf(Al.x), A1 = -__expf(Al.y),
                A2 = -__expf(Al.z), A3 = -__expf(Al.w);
    const int t0 = c * CL;
    const float* dl = delta + ((size_t)(b << 10) + t0) * DI + d;
    const float* uu = u_buf + ((size_t)(b << 10) + t0) * DI + d;
    const float* xb = x_dbl + ((size_t)(b << 10) + t0) * 144 + 16 + j * 4;
    float h0 = 0.f, h1 = 0.f, h2 = 0.f, h3 = 0.f;
    float p0 = 1.f, p1 = 1.f, p2 = 1.f, p3 = 1.f;
    for (int t = 0; t < CL; t++) {
        float dt_ = dl[t * DI];
        float ut  = uu[t * DI];
        float4 B4 = *(const float4*)(xb + t * 144);
        float du = dt_ * ut;
        float e0 = __expf(dt_ * A0), e1 = __expf(dt_ * A1),
              e2 = __expf(dt_ * A2), e3 = __expf(dt_ * A3);
        h0 = fmaf(e0, h0, du * B4.x);
        h1 = fmaf(e1, h1, du * B4.y);
        h2 = fmaf(e2, h2, du * B4.z);
        h3 = fmaf(e3, h3, du * B4.w);
        p0 *= e0; p1 *= e1; p2 *= e2; p3 *= e3;
    }
    size_t o = ((size_t)((c << 11) + (b << 9) + d) << 6) + j * 4;
    *(float4*)(hend + o)  = make_float4(h0, h1, h2, h3);
    *(float4*)(decay + o) = make_float4(p0, p1, p2, p3);
}

// ---------------------------------------------------------------------------
// Chunk combine: per (b,d,s) thread, sequential over 16 chunks, in place:
// hend[c] is replaced by the TRUE chunk-start state.
// ---------------------------------------------------------------------------
__global__ __launch_bounds__(256) void k_scan_comb(
    float* __restrict__ hend, const float* __restrict__ decay)
{
    const int idx = blockIdx.x * 256 + threadIdx.x;  // 0..131071
    float h = 0.f;
#pragma unroll
    for (int c = 0; c < NC; c++) {
        size_t o = ((size_t)c << 17) + idx;
        float he = hend[o];
        float de = decay[o];
        hend[o] = h;
        h = fmaf(de, h, he);
    }
}

// ---------------------------------------------------------------------------
// Pass 2: re-run recurrence from true chunk-start state, emit y.
// y reduction: 3 in-register fma over 4 states + 4 shfl_xor over 16 lanes.
// ---------------------------------------------------------------------------
__global__ __launch_bounds__(256) void k_scan_p2(
    const float* __restrict__ delta, const float* __restrict__ u_buf,
    const float* __restrict__ x_dbl, const float* __restrict__ A_log,
    const float* __restrict__ Dp, const float* __restrict__ hstart,
    float* __restrict__ y_buf)
{
    const int wid = (blockIdx.x << 2) + (threadIdx.x >> 6);
    const int lane = threadIdx.x & 63;
    const int g = lane >> 4, j = lane & 15;
    const int d = ((wid & 127) << 2) + g;
    const int c = (wid >> 7) & 15;
    const int b = wid >> 11;
    float4 Al = *(const float4*)(A_log + d * DSTATE + j * 4);
    const float A0 = -__expf(Al.x), A1 = -__expf(Al.y),
                A2 = -__expf(Al.z), A3 = -__expf(Al.w);
    const float Dd = Dp[d];
    float4 h4 = *(const float4*)(hstart + (((size_t)((c << 11) + (b << 9) + d)) << 6) + j * 4);
    float h0 = h4.x, h1 = h4.y, h2 = h4.z, h3 = h4.w;
    const int t0 = c * CL;
    const float* dl = delta + ((size_t)(b << 10) + t0) * DI + d;
    const float* uu = u_buf + ((size_t)(b << 10) + t0) * DI + d;
    const float* xb = x_dbl + ((size_t)(b << 10) + t0) * 144 + 16 + j * 4;
    const float* xc = x_dbl + ((size_t)(b << 10) + t0) * 144 + 80 + j * 4;
    float* yo = y_buf + ((size_t)(b << 10) + t0) * DI + d;
    for (int t = 0; t < CL; t++) {
        float dt_ = dl[t * DI];
        float ut  = uu[t * DI];
        float4 B4 = *(const float4*)(xb + t * 144);
        float4 C4 = *(const float4*)(xc + t * 144);
        float du = dt_ * ut;
        float e0 = __expf(dt_ * A0), e1 = __expf(dt_ * A1),
              e2 = __expf(dt_ * A2), e3 = __expf(dt_ * A3);
        h0 = fmaf(e0, h0, du * B4.x);
        h1 = fmaf(e1, h1, du * B4.y);
        h2 = fmaf(e2, h2, du * B4.z);
        h3 = fmaf(e3, h3, du * B4.w);
        float p = h0 * C4.x;
        p = fmaf(h1, C4.y, p);
        p = fmaf(h2, C4.z, p);
        p = fmaf(h3, C4.w, p);
        p += __shfl_xor(p, 1);
        p += __shfl_xor(p, 2);
        p += __shfl_xor(p, 4);
        p += __shfl_xor(p, 8);
        if (j == 0) yo[t * DI] = fmaf(ut, Dd, p);
    }
}

// ---------------------------------------------------------------------------
// Out GEMM with fused gating + residual, NCHW store.
// ---------------------------------------------------------------------------
__global__ __launch_bounds__(256) void k_gemm_out(
    const float* __restrict__ Y, const float* __restrict__ XZ,
    const float* __restrict__ W, const float* __restrict__ x_seq,
    float* __restrict__ out)
{
    __shared__ float As[16][64];
    __shared__ float Ws[16][64];
    const int tid = threadIdx.x;
    const int m0 = blockIdx.x * 64;
    const int n0 = blockIdx.y * 64;
    const int tm = tid & 15, tn = tid >> 4;
    const int row = tid >> 2, kq = tid & 3;
    float acc[4][4] = {};

    for (int k0 = 0; k0 < 512; k0 += 16) {
        float4 y4 = *(const float4*)(Y + (size_t)(m0 + row) * DI + k0 + kq * 4);
        float4 z4 = *(const float4*)(XZ + (size_t)(m0 + row) * 1024 + 512 + k0 + kq * 4);
        As[kq * 4 + 0][row] = y4.x * silu_f(z4.x);
        As[kq * 4 + 1][row] = y4.y * silu_f(z4.y);
        As[kq * 4 + 2][row] = y4.z * silu_f(z4.z);
        As[kq * 4 + 3][row] = y4.w * silu_f(z4.w);
        float4 w4 = *(const float4*)(W + (size_t)(n0 + row) * DI + k0 + kq * 4);
        Ws[kq * 4 + 0][row] = w4.x;
        Ws[kq * 4 + 1][row] = w4.y;
        Ws[kq * 4 + 2][row] = w4.z;
        Ws[kq * 4 + 3][row] = w4.w;
        __syncthreads();
#pragma unroll
        for (int k = 0; k < 16; k++) {
            float4 av = *(const float4*)&As[k][tm * 4];
            float4 wv = *(const float4*)&Ws[k][tn * 4];
            float a_[4] = {av.x, av.y, av.z, av.w};
            float w_[4] = {wv.x, wv.y, wv.z, wv.w};
#pragma unroll
            for (int i = 0; i < 4; i++)
#pragma unroll
                for (int j = 0; j < 4; j++)
                    acc[i][j] = fmaf(a_[i], w_[j], acc[i][j]);
        }
        __syncthreads();
    }

    const int b = m0 >> 10;
    const int l0 = (m0 & 1023) + tm * 4;
#pragma unroll
    for (int j = 0; j < 4; j++) {
        int n = n0 + tn * 4 + j;
        float r0 = acc[0][j] + x_seq[(size_t)(m0 + tm * 4 + 0) * DM + n];
        float r1 = acc[1][j] + x_seq[(size_t)(m0 + tm * 4 + 1) * DM + n];
        float r2 = acc[2][j] + x_seq[(size_t)(m0 + tm * 4 + 2) * DM + n];
        float r3 = acc[3][j] + x_seq[(size_t)(m0 + tm * 4 + 3) * DM + n];
        *(float4*)(out + (size_t)(b * DM + n) * LL + l0) = make_float4(r0, r1, r2, r3);
    }
}

extern "C" void kernel_launch(void* const* d_in, const int* in_sizes, int n_in,
                              void* d_out, int out_size, void* d_ws, size_t ws_size,
                              hipStream_t stream)
{
    const float* x         = (const float*)d_in[0];
    const float* w_proj    = (const float*)d_in[1];
    const float* ln_g      = (const float*)d_in[2];
    const float* ln_b      = (const float*)d_in[3];
    const float* in_proj_w = (const float*)d_in[4];
    const float* conv_w    = (const float*)d_in[5];
    const float* conv_b    = (const float*)d_in[6];
    const float* x_proj_w  = (const float*)d_in[7];
    const float* dt_proj_w = (const float*)d_in[8];
    const float* dt_proj_b = (const float*)d_in[9];
    const float* A_log     = (const float*)d_in[10];
    const float* Dp        = (const float*)d_in[11];
    const float* out_proj_w= (const float*)d_in[12];
    float* out = (float*)d_out;

    float* ws    = (float*)d_ws;
    float* x_seq = ws;                     // 4096*256
    float* xn    = ws + 1 * 1048576;       // 4096*256
    float* xz    = ws + 2 * 1048576;       // 4096*1024
    float* u_buf = ws + 6 * 1048576;       // 4096*512
    float* x_dbl = ws + 8 * 1048576;       // 4096*144
    float* delta = ws + 9 * 1048576;       // 4096*512
    float* y_buf = ws + 11 * 1048576;      // 4096*512
    float* hend  = ws + 13 * 1048576;      // 16*2048*64 = 2M (becomes hstart)
    float* decay = ws + 15 * 1048576;      // 2M   (total 17M floats = 68 MB)

    k_proj_ln<<<dim3(MM / 4), dim3(256), 0, stream>>>(x, w_proj, ln_g, ln_b, x_seq, xn);
    k_gemm<<<dim3(MM / 64, 1024 / 64), dim3(256), 0, stream>>>(
        xn, in_proj_w, xz, 1024, 256, 256, 256, 1024);
    k_conv_silu<<<dim3(Bsz * LL * DI / 256), dim3(256), 0, stream>>>(xz, conv_w, conv_b, u_buf);
    k_gemm<<<dim3(MM / 64, 3), dim3(256), 0, stream>>>(
        u_buf, x_proj_w, x_dbl, 144, 512, 512, 512, 144);
    k_delta<<<dim3(MM), dim3(256), 0, stream>>>(x_dbl, dt_proj_w, dt_proj_b, delta);
    // chunked scan
    k_scan_p1<<<dim3(2048), dim3(256), 0, stream>>>(delta, u_buf, x_dbl, A_log, hend, decay);
    k_scan_comb<<<dim3(512), dim3(256), 0, stream>>>(hend, decay);
    k_scan_p2<<<dim3(2048), dim3(256), 0, stream>>>(delta, u_buf, x_dbl, A_log, Dp, hend, y_buf);
    k_gemm_out<<<dim3(MM / 64, 256 / 64), dim3(256), 0, stream>>>(
        y_buf, xz, out_proj_w, x_seq, out);
}

// Round 3
// 263.223 us; speedup vs baseline: 2.7054x; 1.1386x over previous
//
#include <hip/hip_runtime.h>
#include <hip/hip_bf16.h>
#include <math.h>

#define Bsz 4
#define CIN 128
#define LL 1024
#define DM 256
#define DI 512
#define DSTATE 64
#define DR 16
#define MM (Bsz * LL)   // 4096
#define NC 16           // scan chunks
#define CL 64           // chunk length (LL/NC)

typedef short bf16x8 __attribute__((ext_vector_type(8)));
typedef float f32x4 __attribute__((ext_vector_type(4)));

__device__ __forceinline__ float silu_f(float x) {
    return x / (1.0f + __expf(-x));
}

__device__ __forceinline__ unsigned short f2bf(float f) {
    __hip_bfloat16 h = __float2bfloat16(f);
    unsigned short u;
    __builtin_memcpy(&u, &h, sizeof(u));
    return u;
}

// ---------------------------------------------------------------------------
// Cast the three GEMM weight matrices to bf16 (one launch).
// ---------------------------------------------------------------------------
__global__ __launch_bounds__(256) void k_cast_w(
    const float* __restrict__ w_in, const float* __restrict__ w_x,
    const float* __restrict__ w_out, unsigned short* __restrict__ o_in,
    unsigned short* __restrict__ o_x, unsigned short* __restrict__ o_out)
{
    int i = blockIdx.x * 256 + threadIdx.x;
    if (i < 262144)       o_in[i]           = f2bf(w_in[i]);
    else if (i < 335872)  o_x[i - 262144]   = f2bf(w_x[i - 262144]);
    else                  o_out[i - 335872] = f2bf(w_out[i - 335872]);
}

// ---------------------------------------------------------------------------
// K1: x_seq[m][o] = sum_c x[b,c,l]*w_proj[o,c];  LayerNorm -> xn (bf16)
// ---------------------------------------------------------------------------
__global__ __launch_bounds__(256) void k_proj_ln(
    const float* __restrict__ x, const float* __restrict__ w_proj,
    const float* __restrict__ ln_g, const float* __restrict__ ln_b,
    float* __restrict__ x_seq, unsigned short* __restrict__ xn_bf)
{
    __shared__ float xv[4][128];
    __shared__ float sSum[4][4], sSum2[4][4];
    __shared__ float sMean[4], sRstd[4];
    const int m0 = blockIdx.x * 4;
    const int b = m0 >> 10;
    const int l0 = m0 & 1023;
    const int tid = threadIdx.x;

    for (int idx = tid; idx < 512; idx += 256) {
        int c = idx >> 2, p = idx & 3;
        xv[p][c] = x[(b * CIN + c) * LL + l0 + p];
    }
    __syncthreads();

    const int o = tid;
    float acc[4] = {0.f, 0.f, 0.f, 0.f};
    const float4* wr = (const float4*)(w_proj + o * CIN);
#pragma unroll 8
    for (int i = 0; i < 32; i++) {
        float4 w4 = wr[i];
#pragma unroll
        for (int p = 0; p < 4; p++) {
            float4 x4 = ((const float4*)xv[p])[i];
            acc[p] = fmaf(w4.x, x4.x, acc[p]);
            acc[p] = fmaf(w4.y, x4.y, acc[p]);
            acc[p] = fmaf(w4.z, x4.z, acc[p]);
            acc[p] = fmaf(w4.w, x4.w, acc[p]);
        }
    }
    const int lane = tid & 63, wid = tid >> 6;
#pragma unroll
    for (int p = 0; p < 4; p++) {
        float v = acc[p], v2 = v * v;
#pragma unroll
        for (int off = 32; off; off >>= 1) {
            v  += __shfl_xor(v, off);
            v2 += __shfl_xor(v2, off);
        }
        if (lane == 0) { sSum[p][wid] = v; sSum2[p][wid] = v2; }
    }
    __syncthreads();
    if (tid < 4) {
        int p = tid;
        float s  = sSum[p][0] + sSum[p][1] + sSum[p][2] + sSum[p][3];
        float s2 = sSum2[p][0] + sSum2[p][1] + sSum2[p][2] + sSum2[p][3];
        float mean = s * (1.0f / 256.0f);
        float var  = s2 * (1.0f / 256.0f) - mean * mean;
        sMean[p] = mean;
        sRstd[p] = rsqrtf(var + 1e-5f);
    }
    __syncthreads();
    const float g = ln_g[o], bb = ln_b[o];
#pragma unroll
    for (int p = 0; p < 4; p++) {
        int m = m0 + p;
        x_seq[m * DM + o] = acc[p];
        xn_bf[m * DM + o] = f2bf((acc[p] - sMean[p]) * sRstd[p] * g + bb);
    }
}

// ---------------------------------------------------------------------------
// bf16 MFMA GEMM: C[m][n] = sum_k A[m*K+k] * W[n*K+k]   (fp32 out)
// 128x128 tile, BK=32, 256 threads = 4 waves, each wave a 64x64 quadrant.
// M % 128 == 0, K % 32 == 0; N guarded (W rows >= N read as zero).
// ---------------------------------------------------------------------------
__global__ __launch_bounds__(256) void k_gemm_bf(
    const unsigned short* __restrict__ A, const unsigned short* __restrict__ W,
    float* __restrict__ C, int N, int K, int ldc)
{
    __shared__ unsigned short As[128][40];
    __shared__ unsigned short Ws[128][40];
    const int tid = threadIdx.x;
    const int m0 = blockIdx.x * 128, n0 = blockIdx.y * 128;
    const int wave = tid >> 6, lane = tid & 63;
    const int quad = lane >> 4, tcol = lane & 15;
    const int wm = (wave & 1) << 6, wn = (wave >> 1) << 6;
    f32x4 zero = {0.f, 0.f, 0.f, 0.f};
    f32x4 acc[4][4];
#pragma unroll
    for (int i = 0; i < 4; i++)
#pragma unroll
        for (int j = 0; j < 4; j++) acc[i][j] = zero;

    for (int k0 = 0; k0 < K; k0 += 32) {
#pragma unroll
        for (int ch = 0; ch < 2; ch++) {
            int id = tid + ch * 256;
            int r = id >> 2, c = (id & 3) * 8;
            *(bf16x8*)&As[r][c] = *(const bf16x8*)&A[(size_t)(m0 + r) * K + k0 + c];
            int wrow = n0 + r;
            bf16x8 wv = {0, 0, 0, 0, 0, 0, 0, 0};
            if (wrow < N) wv = *(const bf16x8*)&W[(size_t)wrow * K + k0 + c];
            *(bf16x8*)&Ws[r][c] = wv;
        }
        __syncthreads();
        bf16x8 af[4], bfr[4];
#pragma unroll
        for (int i = 0; i < 4; i++)
            af[i] = *(const bf16x8*)&As[wm + i * 16 + tcol][quad * 8];
#pragma unroll
        for (int j = 0; j < 4; j++)
            bfr[j] = *(const bf16x8*)&Ws[wn + j * 16 + tcol][quad * 8];
#pragma unroll
        for (int i = 0; i < 4; i++)
#pragma unroll
            for (int j = 0; j < 4; j++)
                acc[i][j] = __builtin_amdgcn_mfma_f32_16x16x32_bf16(
                    af[i], bfr[j], acc[i][j], 0, 0, 0);
        __syncthreads();
    }
#pragma unroll
    for (int i = 0; i < 4; i++) {
        int m = m0 + wm + i * 16 + quad * 4;
#pragma unroll
        for (int j = 0; j < 4; j++) {
            int n = n0 + wn + j * 16 + tcol;
            if (n < N) {
#pragma unroll
                for (int r = 0; r < 4; r++)
                    C[(size_t)(m + r) * ldc + n] = acc[i][j][r];
            }
        }
    }
}

// ---------------------------------------------------------------------------
// Depthwise causal conv (k=4) + bias + SiLU -> fp32 u (scan) + bf16 u (GEMM)
// ---------------------------------------------------------------------------
__global__ __launch_bounds__(256) void k_conv_silu(
    const float* __restrict__ xz, const float* __restrict__ conv_w,
    const float* __restrict__ conv_b, float* __restrict__ u_buf,
    unsigned short* __restrict__ u_bf)
{
    const int idx = blockIdx.x * 256 + threadIdx.x;
    const int d = idx & 511;
    const int l = (idx >> 9) & 1023;
    const int b = idx >> 19;
    float acc = conv_b[d];
    const float* w = conv_w + d * 4;
#pragma unroll
    for (int j = 0; j < 4; j++) {
        int li = l - 3 + j;
        if (li >= 0)
            acc = fmaf(xz[(size_t)((b << 10) + li) * 1024 + d], w[j], acc);
    }
    float v = silu_f(acc);
    u_buf[idx] = v;
    u_bf[idx] = f2bf(v);
}

// ---------------------------------------------------------------------------
// delta = softplus(dt @ dt_proj_w^T + dt_proj_b)
// ---------------------------------------------------------------------------
__global__ __launch_bounds__(256) void k_delta(
    const float* __restrict__ x_dbl, const float* __restrict__ dtw,
    const float* __restrict__ dtb, float* __restrict__ delta)
{
    __shared__ float dtv[16];
    const int m = blockIdx.x;
    const int tid = threadIdx.x;
    if (tid < 16) dtv[tid] = x_dbl[(size_t)m * 144 + tid];
    __syncthreads();
#pragma unroll
    for (int nn = 0; nn < 2; nn++) {
        int n = tid + nn * 256;
        float acc = dtb[n];
        const float4* wr = (const float4*)(dtw + n * 16);
#pragma unroll
        for (int r4 = 0; r4 < 4; r4++) {
            float4 w4 = wr[r4];
            float4 d4 = ((const float4*)dtv)[r4];
            acc = fmaf(w4.x, d4.x, acc);
            acc = fmaf(w4.y, d4.y, acc);
            acc = fmaf(w4.z, d4.z, acc);
            acc = fmaf(w4.w, d4.w, acc);
        }
        delta[(size_t)m * DI + n] = (acc > 20.0f) ? acc : log1pf(__expf(acc));
    }
}

// ---------------------------------------------------------------------------
// Chunked selective scan, pass 1: local recurrence from h=0.
// ---------------------------------------------------------------------------
__global__ __launch_bounds__(256) void k_scan_p1(
    const float* __restrict__ delta, const float* __restrict__ u_buf,
    const float* __restrict__ x_dbl, const float* __restrict__ A_log,
    float* __restrict__ hend, float* __restrict__ decay)
{
    const int wid = (blockIdx.x << 2) + (threadIdx.x >> 6);
    const int lane = threadIdx.x & 63;
    const int g = lane >> 4, j = lane & 15;
    const int d = ((wid & 127) << 2) + g;
    const int c = (wid >> 7) & 15;
    const int b = wid >> 11;
    float4 Al = *(const float4*)(A_log + d * DSTATE + j * 4);
    const float A0 = -__expf(Al.x), A1 = -__expf(Al.y),
                A2 = -__expf(Al.z), A3 = -__expf(Al.w);
    const int t0 = c * CL;
    const float* dl = delta + ((size_t)(b << 10) + t0) * DI + d;
    const float* uu = u_buf + ((size_t)(b << 10) + t0) * DI + d;
    const float* xb = x_dbl + ((size_t)(b << 10) + t0) * 144 + 16 + j * 4;
    float h0 = 0.f, h1 = 0.f, h2 = 0.f, h3 = 0.f;
    float p0 = 1.f, p1 = 1.f, p2 = 1.f, p3 = 1.f;
    for (int t = 0; t < CL; t++) {
        float dt_ = dl[t * DI];
        float ut  = uu[t * DI];
        float4 B4 = *(const float4*)(xb + t * 144);
        float du = dt_ * ut;
        float e0 = __expf(dt_ * A0), e1 = __expf(dt_ * A1),
              e2 = __expf(dt_ * A2), e3 = __expf(dt_ * A3);
        h0 = fmaf(e0, h0, du * B4.x);
        h1 = fmaf(e1, h1, du * B4.y);
        h2 = fmaf(e2, h2, du * B4.z);
        h3 = fmaf(e3, h3, du * B4.w);
        p0 *= e0; p1 *= e1; p2 *= e2; p3 *= e3;
    }
    size_t o = ((size_t)((c << 11) + (b << 9) + d) << 6) + j * 4;
    *(float4*)(hend + o)  = make_float4(h0, h1, h2, h3);
    *(float4*)(decay + o) = make_float4(p0, p1, p2, p3);
}

// ---------------------------------------------------------------------------
// Chunk combine (in place): hend[c] <- true chunk-start state.
// ---------------------------------------------------------------------------
__global__ __launch_bounds__(256) void k_scan_comb(
    float* __restrict__ hend, const float* __restrict__ decay)
{
    const int idx = blockIdx.x * 256 + threadIdx.x;
    float h = 0.f;
#pragma unroll
    for (int c = 0; c < NC; c++) {
        size_t o = ((size_t)c << 17) + idx;
        float he = hend[o];
        float de = decay[o];
        hend[o] = h;
        h = fmaf(de, h, he);
    }
}

// ---------------------------------------------------------------------------
// Pass 2: re-run from true start state; fuse gate: g = (y+u*D)*silu(z) -> bf16
// ---------------------------------------------------------------------------
__global__ __launch_bounds__(256) void k_scan_p2(
    const float* __restrict__ delta, const float* __restrict__ u_buf,
    const float* __restrict__ x_dbl, const float* __restrict__ A_log,
    const float* __restrict__ Dp, const float* __restrict__ hstart,
    const float* __restrict__ xz, unsigned short* __restrict__ g_bf)
{
    const int wid = (blockIdx.x << 2) + (threadIdx.x >> 6);
    const int lane = threadIdx.x & 63;
    const int g = lane >> 4, j = lane & 15;
    const int d = ((wid & 127) << 2) + g;
    const int c = (wid >> 7) & 15;
    const int b = wid >> 11;
    float4 Al = *(const float4*)(A_log + d * DSTATE + j * 4);
    const float A0 = -__expf(Al.x), A1 = -__expf(Al.y),
                A2 = -__expf(Al.z), A3 = -__expf(Al.w);
    const float Dd = Dp[d];
    float4 h4 = *(const float4*)(hstart + (((size_t)((c << 11) + (b << 9) + d)) << 6) + j * 4);
    float h0 = h4.x, h1 = h4.y, h2 = h4.z, h3 = h4.w;
    const int t0 = c * CL;
    const float* dl = delta + ((size_t)(b << 10) + t0) * DI + d;
    const float* uu = u_buf + ((size_t)(b << 10) + t0) * DI + d;
    const float* xb = x_dbl + ((size_t)(b << 10) + t0) * 144 + 16 + j * 4;
    const float* xc = x_dbl + ((size_t)(b << 10) + t0) * 144 + 80 + j * 4;
    const float* zz = xz + ((size_t)(b << 10) + t0) * 1024 + 512 + d;
    unsigned short* go = g_bf + ((size_t)(b << 10) + t0) * DI + d;
    for (int t = 0; t < CL; t++) {
        float dt_ = dl[t * DI];
        float ut  = uu[t * DI];
        float4 B4 = *(const float4*)(xb + t * 144);
        float4 C4 = *(const float4*)(xc + t * 144);
        float du = dt_ * ut;
        float e0 = __expf(dt_ * A0), e1 = __expf(dt_ * A1),
              e2 = __expf(dt_ * A2), e3 = __expf(dt_ * A3);
        h0 = fmaf(e0, h0, du * B4.x);
        h1 = fmaf(e1, h1, du * B4.y);
        h2 = fmaf(e2, h2, du * B4.z);
        h3 = fmaf(e3, h3, du * B4.w);
        float p = h0 * C4.x;
        p = fmaf(h1, C4.y, p);
        p = fmaf(h2, C4.z, p);
        p = fmaf(h3, C4.w, p);
        p += __shfl_xor(p, 1);
        p += __shfl_xor(p, 2);
        p += __shfl_xor(p, 4);
        p += __shfl_xor(p, 8);
        if (j == 0) {
            float yv = fmaf(ut, Dd, p);
            float zv = zz[t * 1024];
            go[t * DI] = f2bf(yv * silu_f(zv));
        }
    }
}

// ---------------------------------------------------------------------------
// Out GEMM (bf16 MFMA): C = g @ out_proj_w^T + x_seq, NCHW float4 store.
// M=4096, N=256, K=512.
// ---------------------------------------------------------------------------
__global__ __launch_bounds__(256) void k_gemm_out_bf(
    const unsigned short* __restrict__ A, const unsigned short* __restrict__ W,
    const float* __restrict__ x_seq, float* __restrict__ out)
{
    __shared__ unsigned short As[128][40];
    __shared__ unsigned short Ws[128][40];
    const int tid = threadIdx.x;
    const int m0 = blockIdx.x * 128, n0 = blockIdx.y * 128;
    const int wave = tid >> 6, lane = tid & 63;
    const int quad = lane >> 4, tcol = lane & 15;
    const int wm = (wave & 1) << 6, wn = (wave >> 1) << 6;
    f32x4 zero = {0.f, 0.f, 0.f, 0.f};
    f32x4 acc[4][4];
#pragma unroll
    for (int i = 0; i < 4; i++)
#pragma unroll
        for (int j = 0; j < 4; j++) acc[i][j] = zero;

    for (int k0 = 0; k0 < 512; k0 += 32) {
#pragma unroll
        for (int ch = 0; ch < 2; ch++) {
            int id = tid + ch * 256;
            int r = id >> 2, c = (id & 3) * 8;
            *(bf16x8*)&As[r][c] = *(const bf16x8*)&A[(size_t)(m0 + r) * 512 + k0 + c];
            *(bf16x8*)&Ws[r][c] = *(const bf16x8*)&W[(size_t)(n0 + r) * 512 + k0 + c];
        }
        __syncthreads();
        bf16x8 af[4], bfr[4];
#pragma unroll
        for (int i = 0; i < 4; i++)
            af[i] = *(const bf16x8*)&As[wm + i * 16 + tcol][quad * 8];
#pragma unroll
        for (int j = 0; j < 4; j++)
            bfr[j] = *(const bf16x8*)&Ws[wn + j * 16 + tcol][quad * 8];
#pragma unroll
        for (int i = 0; i < 4; i++)
#pragma unroll
            for (int j = 0; j < 4; j++)
                acc[i][j] = __builtin_amdgcn_mfma_f32_16x16x32_bf16(
                    af[i], bfr[j], acc[i][j], 0, 0, 0);
        __syncthreads();
    }

    const int b = m0 >> 10;
#pragma unroll
    for (int i = 0; i < 4; i++) {
        int mb = m0 + wm + i * 16 + quad * 4;
        int l0 = mb & 1023;
#pragma unroll
        for (int j = 0; j < 4; j++) {
            int n = n0 + wn + j * 16 + tcol;
            float r0 = acc[i][j][0] + x_seq[(size_t)(mb + 0) * DM + n];
            float r1 = acc[i][j][1] + x_seq[(size_t)(mb + 1) * DM + n];
            float r2 = acc[i][j][2] + x_seq[(size_t)(mb + 2) * DM + n];
            float r3 = acc[i][j][3] + x_seq[(size_t)(mb + 3) * DM + n];
            *(float4*)(out + (size_t)(b * DM + n) * LL + l0) = make_float4(r0, r1, r2, r3);
        }
    }
}

extern "C" void kernel_launch(void* const* d_in, const int* in_sizes, int n_in,
                              void* d_out, int out_size, void* d_ws, size_t ws_size,
                              hipStream_t stream)
{
    const float* x         = (const float*)d_in[0];
    const float* w_proj    = (const float*)d_in[1];
    const float* ln_g      = (const float*)d_in[2];
    const float* ln_b      = (const float*)d_in[3];
    const float* in_proj_w = (const float*)d_in[4];
    const float* conv_w    = (const float*)d_in[5];
    const float* conv_b    = (const float*)d_in[6];
    const float* x_proj_w  = (const float*)d_in[7];
    const float* dt_proj_w = (const float*)d_in[8];
    const float* dt_proj_b = (const float*)d_in[9];
    const float* A_log     = (const float*)d_in[10];
    const float* Dp        = (const float*)d_in[11];
    const float* out_proj_w= (const float*)d_in[12];
    float* out = (float*)d_out;

    const size_t U = 1048576;
    float* ws    = (float*)d_ws;
    float* x_seq = ws;                 // [0,1)U
    float* xz    = ws + 1 * U;         // [1,5)U
    float* u_buf = ws + 5 * U;         // [5,7)U
    float* x_dbl = ws + 7 * U;         // [7,8)U (589824 used)
    float* delta = ws + 8 * U;         // [8,10)U
    float* hend  = ws + 10 * U;        // [10,12)U
    float* decay = ws + 12 * U;        // [12,14)U
    unsigned short* bz      = (unsigned short*)(ws + 14 * U);
    unsigned short* g_bf    = bz;                 // 2,097,152
    unsigned short* xn_bf   = bz + 2097152;       // 1,048,576
    unsigned short* u_bf    = bz + 3145728;       // 2,097,152
    unsigned short* w_in_bf = bz + 5242880;       // 262,144
    unsigned short* w_x_bf  = bz + 5505024;       //  73,728
    unsigned short* w_out_bf= bz + 5578752;       // 131,072

    k_cast_w<<<dim3(1824), dim3(256), 0, stream>>>(
        in_proj_w, x_proj_w, out_proj_w, w_in_bf, w_x_bf, w_out_bf);
    k_proj_ln<<<dim3(MM / 4), dim3(256), 0, stream>>>(x, w_proj, ln_g, ln_b, x_seq, xn_bf);
    // in_proj: xn(4096x256) @ W^T(256x1024) -> xz
    k_gemm_bf<<<dim3(32, 8), dim3(256), 0, stream>>>(xn_bf, w_in_bf, xz, 1024, 256, 1024);
    k_conv_silu<<<dim3(Bsz * LL * DI / 256), dim3(256), 0, stream>>>(
        xz, conv_w, conv_b, u_buf, u_bf);
    // x_proj: u(4096x512) @ W^T(512x144) -> x_dbl
    k_gemm_bf<<<dim3(32, 2), dim3(256), 0, stream>>>(u_bf, w_x_bf, x_dbl, 144, 512, 144);
    k_delta<<<dim3(MM), dim3(256), 0, stream>>>(x_dbl, dt_proj_w, dt_proj_b, delta);
    k_scan_p1<<<dim3(2048), dim3(256), 0, stream>>>(delta, u_buf, x_dbl, A_log, hend, decay);
    k_scan_comb<<<dim3(512), dim3(256), 0, stream>>>(hend, decay);
    k_scan_p2<<<dim3(2048), dim3(256), 0, stream>>>(
        delta, u_buf, x_dbl, A_log, Dp, hend, xz, g_bf);
    k_gemm_out_bf<<<dim3(32, 2), dim3(256), 0, stream>>>(g_bf, w_out_bf, x_seq, out);
}

// Round 4
// 256.506 us; speedup vs baseline: 2.7762x; 1.0262x over previous
//
#include <hip/hip_runtime.h>
#include <hip/hip_bf16.h>
#include <math.h>

#define Bsz 4
#define CIN 128
#define LL 1024
#define DM 256
#define DI 512
#define DSTATE 64
#define DR 16
#define MM (Bsz * LL)   // 4096
#define NC 16           // scan chunks
#define CL 64           // chunk length (LL/NC)

typedef short bf16x8 __attribute__((ext_vector_type(8)));
typedef float f32x4 __attribute__((ext_vector_type(4)));

__device__ __forceinline__ float silu_f(float x) {
    return x / (1.0f + __expf(-x));
}

__device__ __forceinline__ unsigned short f2bf(float f) {
    __hip_bfloat16 h = __float2bfloat16(f);
    unsigned short u;
    __builtin_memcpy(&u, &h, sizeof(u));
    return u;
}

// ---------------------------------------------------------------------------
// Cast the three GEMM weight matrices to bf16.
// ---------------------------------------------------------------------------
__global__ __launch_bounds__(256) void k_cast_w(
    const float* __restrict__ w_in, const float* __restrict__ w_x,
    const float* __restrict__ w_out, unsigned short* __restrict__ o_in,
    unsigned short* __restrict__ o_x, unsigned short* __restrict__ o_out)
{
    int i = blockIdx.x * 256 + threadIdx.x;
    if (i < 262144)       o_in[i]           = f2bf(w_in[i]);
    else if (i < 335872)  o_x[i - 262144]   = f2bf(w_x[i - 262144]);
    else                  o_out[i - 335872] = f2bf(w_out[i - 335872]);
}

// ---------------------------------------------------------------------------
// K1: x_seq[m][o] = sum_c x[b,c,l]*w_proj[o,c];  LayerNorm -> xn (bf16)
// ---------------------------------------------------------------------------
__global__ __launch_bounds__(256) void k_proj_ln(
    const float* __restrict__ x, const float* __restrict__ w_proj,
    const float* __restrict__ ln_g, const float* __restrict__ ln_b,
    float* __restrict__ x_seq, unsigned short* __restrict__ xn_bf)
{
    __shared__ float xv[4][128];
    __shared__ float sSum[4][4], sSum2[4][4];
    __shared__ float sMean[4], sRstd[4];
    const int m0 = blockIdx.x * 4;
    const int b = m0 >> 10;
    const int l0 = m0 & 1023;
    const int tid = threadIdx.x;

    for (int idx = tid; idx < 512; idx += 256) {
        int c = idx >> 2, p = idx & 3;
        xv[p][c] = x[(b * CIN + c) * LL + l0 + p];
    }
    __syncthreads();

    const int o = tid;
    float acc[4] = {0.f, 0.f, 0.f, 0.f};
    const float4* wr = (const float4*)(w_proj + o * CIN);
#pragma unroll 8
    for (int i = 0; i < 32; i++) {
        float4 w4 = wr[i];
#pragma unroll
        for (int p = 0; p < 4; p++) {
            float4 x4 = ((const float4*)xv[p])[i];
            acc[p] = fmaf(w4.x, x4.x, acc[p]);
            acc[p] = fmaf(w4.y, x4.y, acc[p]);
            acc[p] = fmaf(w4.z, x4.z, acc[p]);
            acc[p] = fmaf(w4.w, x4.w, acc[p]);
        }
    }
    const int lane = tid & 63, wid = tid >> 6;
#pragma unroll
    for (int p = 0; p < 4; p++) {
        float v = acc[p], v2 = v * v;
#pragma unroll
        for (int off = 32; off; off >>= 1) {
            v  += __shfl_xor(v, off);
            v2 += __shfl_xor(v2, off);
        }
        if (lane == 0) { sSum[p][wid] = v; sSum2[p][wid] = v2; }
    }
    __syncthreads();
    if (tid < 4) {
        int p = tid;
        float s  = sSum[p][0] + sSum[p][1] + sSum[p][2] + sSum[p][3];
        float s2 = sSum2[p][0] + sSum2[p][1] + sSum2[p][2] + sSum2[p][3];
        float mean = s * (1.0f / 256.0f);
        float var  = s2 * (1.0f / 256.0f) - mean * mean;
        sMean[p] = mean;
        sRstd[p] = rsqrtf(var + 1e-5f);
    }
    __syncthreads();
    const float g = ln_g[o], bb = ln_b[o];
#pragma unroll
    for (int p = 0; p < 4; p++) {
        int m = m0 + p;
        x_seq[m * DM + o] = acc[p];
        xn_bf[m * DM + o] = f2bf((acc[p] - sMean[p]) * sRstd[p] * g + bb);
    }
}

// ---------------------------------------------------------------------------
// bf16 MFMA GEMM: C[m][n] = sum_k A[m*K+k] * W[n*K+k]   (fp32 out)
// 128x128 tile, BK=32, 4 waves, wave = 64x64 quadrant. N guarded.
// ---------------------------------------------------------------------------
__global__ __launch_bounds__(256) void k_gemm_bf(
    const unsigned short* __restrict__ A, const unsigned short* __restrict__ W,
    float* __restrict__ C, int N, int K, int ldc)
{
    __shared__ unsigned short As[128][40];
    __shared__ unsigned short Ws[128][40];
    const int tid = threadIdx.x;
    const int m0 = blockIdx.x * 128, n0 = blockIdx.y * 128;
    const int wave = tid >> 6, lane = tid & 63;
    const int quad = lane >> 4, tcol = lane & 15;
    const int wm = (wave & 1) << 6, wn = (wave >> 1) << 6;
    f32x4 zero = {0.f, 0.f, 0.f, 0.f};
    f32x4 acc[4][4];
#pragma unroll
    for (int i = 0; i < 4; i++)
#pragma unroll
        for (int j = 0; j < 4; j++) acc[i][j] = zero;

    for (int k0 = 0; k0 < K; k0 += 32) {
#pragma unroll
        for (int ch = 0; ch < 2; ch++) {
            int id = tid + ch * 256;
            int r = id >> 2, c = (id & 3) * 8;
            *(bf16x8*)&As[r][c] = *(const bf16x8*)&A[(size_t)(m0 + r) * K + k0 + c];
            int wrow = n0 + r;
            bf16x8 wv = {0, 0, 0, 0, 0, 0, 0, 0};
            if (wrow < N) wv = *(const bf16x8*)&W[(size_t)wrow * K + k0 + c];
            *(bf16x8*)&Ws[r][c] = wv;
        }
        __syncthreads();
        bf16x8 af[4], bfr[4];
#pragma unroll
        for (int i = 0; i < 4; i++)
            af[i] = *(const bf16x8*)&As[wm + i * 16 + tcol][quad * 8];
#pragma unroll
        for (int j = 0; j < 4; j++)
            bfr[j] = *(const bf16x8*)&Ws[wn + j * 16 + tcol][quad * 8];
#pragma unroll
        for (int i = 0; i < 4; i++)
#pragma unroll
            for (int j = 0; j < 4; j++)
                acc[i][j] = __builtin_amdgcn_mfma_f32_16x16x32_bf16(
                    af[i], bfr[j], acc[i][j], 0, 0, 0);
        __syncthreads();
    }
#pragma unroll
    for (int i = 0; i < 4; i++) {
        int m = m0 + wm + i * 16 + quad * 4;
#pragma unroll
        for (int j = 0; j < 4; j++) {
            int n = n0 + wn + j * 16 + tcol;
            if (n < N) {
#pragma unroll
                for (int r = 0; r < 4; r++)
                    C[(size_t)(m + r) * ldc + n] = acc[i][j][r];
            }
        }
    }
}

// ---------------------------------------------------------------------------
// Depthwise causal conv (k=4) + bias + SiLU -> fp32 u (scan) + bf16 u (GEMM)
// ---------------------------------------------------------------------------
__global__ __launch_bounds__(256) void k_conv_silu(
    const float* __restrict__ xz, const float* __restrict__ conv_w,
    const float* __restrict__ conv_b, float* __restrict__ u_buf,
    unsigned short* __restrict__ u_bf)
{
    const int idx = blockIdx.x * 256 + threadIdx.x;
    const int d = idx & 511;
    const int l = (idx >> 9) & 1023;
    const int b = idx >> 19;
    float acc = conv_b[d];
    const float* w = conv_w + d * 4;
#pragma unroll
    for (int j = 0; j < 4; j++) {
        int li = l - 3 + j;
        if (li >= 0)
            acc = fmaf(xz[(size_t)((b << 10) + li) * 1024 + d], w[j], acc);
    }
    float v = silu_f(acc);
    u_buf[idx] = v;
    u_bf[idx] = f2bf(v);
}

// ---------------------------------------------------------------------------
// delta = softplus(dt @ dt_proj_w^T + dt_proj_b)
// ---------------------------------------------------------------------------
__global__ __launch_bounds__(256) void k_delta(
    const float* __restrict__ x_dbl, const float* __restrict__ dtw,
    const float* __restrict__ dtb, float* __restrict__ delta)
{
    __shared__ float dtv[16];
    const int m = blockIdx.x;
    const int tid = threadIdx.x;
    if (tid < 16) dtv[tid] = x_dbl[(size_t)m * 144 + tid];
    __syncthreads();
#pragma unroll
    for (int nn = 0; nn < 2; nn++) {
        int n = tid + nn * 256;
        float acc = dtb[n];
        const float4* wr = (const float4*)(dtw + n * 16);
#pragma unroll
        for (int r4 = 0; r4 < 4; r4++) {
            float4 w4 = wr[r4];
            float4 d4 = ((const float4*)dtv)[r4];
            acc = fmaf(w4.x, d4.x, acc);
            acc = fmaf(w4.y, d4.y, acc);
            acc = fmaf(w4.z, d4.z, acc);
            acc = fmaf(w4.w, d4.w, acc);
        }
        delta[(size_t)m * DI + n] = (acc > 20.0f) ? acc : log1pf(__expf(acc));
    }
}

// ---------------------------------------------------------------------------
// Scan pass 1. Wave = 8 groups of 8 lanes; group g -> d = d0+g; lane j holds
// states s = 8j..8j+7.  Local recurrence from h=0; decay = exp(A * sum(dt)).
// wid -> b = wid>>10, c = (wid>>6)&15, d0 = (wid&63)*8.   4096 wids.
// ---------------------------------------------------------------------------
__global__ __launch_bounds__(256) void k_scan_p1(
    const float* __restrict__ delta, const float* __restrict__ u_buf,
    const float* __restrict__ x_dbl, const float* __restrict__ A_log,
    float* __restrict__ hend, float* __restrict__ decay)
{
    const int wid = (blockIdx.x << 2) + (threadIdx.x >> 6);
    const int lane = threadIdx.x & 63;
    const int g = lane >> 3, j = lane & 7;
    const int d = ((wid & 63) << 3) + g;
    const int c = (wid >> 6) & 15;
    const int b = wid >> 10;
    float A[8];
    {
        float4 a0 = *(const float4*)(A_log + d * DSTATE + j * 8);
        float4 a1 = *(const float4*)(A_log + d * DSTATE + j * 8 + 4);
        A[0] = -__expf(a0.x); A[1] = -__expf(a0.y);
        A[2] = -__expf(a0.z); A[3] = -__expf(a0.w);
        A[4] = -__expf(a1.x); A[5] = -__expf(a1.y);
        A[6] = -__expf(a1.z); A[7] = -__expf(a1.w);
    }
    const int t0 = c * CL;
    const float* dl = delta + ((size_t)(b << 10) + t0) * DI + d;
    const float* uu = u_buf + ((size_t)(b << 10) + t0) * DI + d;
    const float* xb = x_dbl + ((size_t)(b << 10) + t0) * 144 + 16 + j * 8;
    float h[8] = {0.f, 0.f, 0.f, 0.f, 0.f, 0.f, 0.f, 0.f};
    float sdt = 0.f;
#pragma unroll 2
    for (int t = 0; t < CL; t++) {
        float dt_ = dl[t * DI];
        float ut  = uu[t * DI];
        float4 B0 = *(const float4*)(xb + t * 144);
        float4 B1 = *(const float4*)(xb + t * 144 + 4);
        float du = dt_ * ut;
        sdt += dt_;
        float Bv[8] = {B0.x, B0.y, B0.z, B0.w, B1.x, B1.y, B1.z, B1.w};
#pragma unroll
        for (int k = 0; k < 8; k++) {
            float e = __expf(dt_ * A[k]);
            h[k] = fmaf(e, h[k], du * Bv[k]);
        }
    }
    size_t o = ((size_t)((c << 11) + (b << 9) + d) << 6) + j * 8;
    *(float4*)(hend + o)     = make_float4(h[0], h[1], h[2], h[3]);
    *(float4*)(hend + o + 4) = make_float4(h[4], h[5], h[6], h[7]);
    *(float4*)(decay + o)     = make_float4(__expf(A[0] * sdt), __expf(A[1] * sdt),
                                            __expf(A[2] * sdt), __expf(A[3] * sdt));
    *(float4*)(decay + o + 4) = make_float4(__expf(A[4] * sdt), __expf(A[5] * sdt),
                                            __expf(A[6] * sdt), __expf(A[7] * sdt));
}

// ---------------------------------------------------------------------------
// Chunk combine (in place): hend[c] <- true chunk-start state.
// ---------------------------------------------------------------------------
__global__ __launch_bounds__(256) void k_scan_comb(
    float* __restrict__ hend, const float* __restrict__ decay)
{
    const int idx = blockIdx.x * 256 + threadIdx.x;
    float h = 0.f;
#pragma unroll
    for (int c = 0; c < NC; c++) {
        size_t o = ((size_t)c << 17) + idx;
        float he = hend[o];
        float de = decay[o];
        hend[o] = h;
        h = fmaf(de, h, he);
    }
}

// ---------------------------------------------------------------------------
// Scan pass 2: re-run from true start; y = <h,C> + u*D (fp32, coalesced).
// Reduce: 7 in-reg fma + 3 shfl_xor over 8 lanes.
// ---------------------------------------------------------------------------
__global__ __launch_bounds__(256) void k_scan_p2(
    const float* __restrict__ delta, const float* __restrict__ u_buf,
    const float* __restrict__ x_dbl, const float* __restrict__ A_log,
    const float* __restrict__ Dp, const float* __restrict__ hstart,
    float* __restrict__ y_buf)
{
    const int wid = (blockIdx.x << 2) + (threadIdx.x >> 6);
    const int lane = threadIdx.x & 63;
    const int g = lane >> 3, j = lane & 7;
    const int d = ((wid & 63) << 3) + g;
    const int c = (wid >> 6) & 15;
    const int b = wid >> 10;
    float A[8];
    {
        float4 a0 = *(const float4*)(A_log + d * DSTATE + j * 8);
        float4 a1 = *(const float4*)(A_log + d * DSTATE + j * 8 + 4);
        A[0] = -__expf(a0.x); A[1] = -__expf(a0.y);
        A[2] = -__expf(a0.z); A[3] = -__expf(a0.w);
        A[4] = -__expf(a1.x); A[5] = -__expf(a1.y);
        A[6] = -__expf(a1.z); A[7] = -__expf(a1.w);
    }
    const float Dd = Dp[d];
    float h[8];
    {
        size_t o = ((size_t)((c << 11) + (b << 9) + d) << 6) + j * 8;
        float4 h0 = *(const float4*)(hstart + o);
        float4 h1 = *(const float4*)(hstart + o + 4);
        h[0] = h0.x; h[1] = h0.y; h[2] = h0.z; h[3] = h0.w;
        h[4] = h1.x; h[5] = h1.y; h[6] = h1.z; h[7] = h1.w;
    }
    const int t0 = c * CL;
    const float* dl = delta + ((size_t)(b << 10) + t0) * DI + d;
    const float* uu = u_buf + ((size_t)(b << 10) + t0) * DI + d;
    const float* xb = x_dbl + ((size_t)(b << 10) + t0) * 144 + 16 + j * 8;
    const float* xc = x_dbl + ((size_t)(b << 10) + t0) * 144 + 80 + j * 8;
    float* yo = y_buf + ((size_t)(b << 10) + t0) * DI + d;
#pragma unroll 2
    for (int t = 0; t < CL; t++) {
        float dt_ = dl[t * DI];
        float ut  = uu[t * DI];
        float4 B0 = *(const float4*)(xb + t * 144);
        float4 B1 = *(const float4*)(xb + t * 144 + 4);
        float4 C0 = *(const float4*)(xc + t * 144);
        float4 C1 = *(const float4*)(xc + t * 144 + 4);
        float du = dt_ * ut;
        float Bv[8] = {B0.x, B0.y, B0.z, B0.w, B1.x, B1.y, B1.z, B1.w};
        float Cv[8] = {C0.x, C0.y, C0.z, C0.w, C1.x, C1.y, C1.z, C1.w};
        float p = 0.f;
#pragma unroll
        for (int k = 0; k < 8; k++) {
            float e = __expf(dt_ * A[k]);
            h[k] = fmaf(e, h[k], du * Bv[k]);
            p = fmaf(h[k], Cv[k], p);
        }
        p += __shfl_xor(p, 1);
        p += __shfl_xor(p, 2);
        p += __shfl_xor(p, 4);
        if (j == 0) yo[t * DI] = fmaf(ut, Dd, p);
    }
}

// ---------------------------------------------------------------------------
// Out GEMM (bf16 MFMA): A = y*silu(z) computed in staging (fp32 -> bf16),
// C = A @ out_proj_w^T + x_seq, NCHW float4 store.  M=4096, N=256, K=512.
// ---------------------------------------------------------------------------
__global__ __launch_bounds__(256) void k_gemm_out_bf(
    const float* __restrict__ Y, const float* __restrict__ XZ,
    const unsigned short* __restrict__ W, const float* __restrict__ x_seq,
    float* __restrict__ out)
{
    __shared__ unsigned short As[128][40];
    __shared__ unsigned short Ws[128][40];
    const int tid = threadIdx.x;
    const int m0 = blockIdx.x * 128, n0 = blockIdx.y * 128;
    const int wave = tid >> 6, lane = tid & 63;
    const int quad = lane >> 4, tcol = lane & 15;
    const int wm = (wave & 1) << 6, wn = (wave >> 1) << 6;
    f32x4 zero = {0.f, 0.f, 0.f, 0.f};
    f32x4 acc[4][4];
#pragma unroll
    for (int i = 0; i < 4; i++)
#pragma unroll
        for (int j = 0; j < 4; j++) acc[i][j] = zero;

    for (int k0 = 0; k0 < 512; k0 += 32) {
#pragma unroll
        for (int ch = 0; ch < 2; ch++) {
            int id = tid + ch * 256;
            int r = id >> 2, cc = (id & 3) * 8;
            int m = m0 + r;
            const float4* yp = (const float4*)(Y + (size_t)m * DI + k0 + cc);
            const float4* zp = (const float4*)(XZ + (size_t)m * 1024 + 512 + k0 + cc);
            float4 y0 = yp[0], y1 = yp[1];
            float4 z0 = zp[0], z1 = zp[1];
            unsigned short gv[8];
            gv[0] = f2bf(y0.x * silu_f(z0.x));
            gv[1] = f2bf(y0.y * silu_f(z0.y));
            gv[2] = f2bf(y0.z * silu_f(z0.z));
            gv[3] = f2bf(y0.w * silu_f(z0.w));
            gv[4] = f2bf(y1.x * silu_f(z1.x));
            gv[5] = f2bf(y1.y * silu_f(z1.y));
            gv[6] = f2bf(y1.z * silu_f(z1.z));
            gv[7] = f2bf(y1.w * silu_f(z1.w));
            *(bf16x8*)&As[r][cc] = *(bf16x8*)gv;
            *(bf16x8*)&Ws[r][cc] = *(const bf16x8*)&W[(size_t)(n0 + r) * 512 + k0 + cc];
        }
        __syncthreads();
        bf16x8 af[4], bfr[4];
#pragma unroll
        for (int i = 0; i < 4; i++)
            af[i] = *(const bf16x8*)&As[wm + i * 16 + tcol][quad * 8];
#pragma unroll
        for (int j = 0; j < 4; j++)
            bfr[j] = *(const bf16x8*)&Ws[wn + j * 16 + tcol][quad * 8];
#pragma unroll
        for (int i = 0; i < 4; i++)
#pragma unroll
            for (int j = 0; j < 4; j++)
                acc[i][j] = __builtin_amdgcn_mfma_f32_16x16x32_bf16(
                    af[i], bfr[j], acc[i][j], 0, 0, 0);
        __syncthreads();
    }

    const int b = m0 >> 10;
#pragma unroll
    for (int i = 0; i < 4; i++) {
        int mb = m0 + wm + i * 16 + quad * 4;
        int l0 = mb & 1023;
#pragma unroll
        for (int j = 0; j < 4; j++) {
            int n = n0 + wn + j * 16 + tcol;
            float r0 = acc[i][j][0] + x_seq[(size_t)(mb + 0) * DM + n];
            float r1 = acc[i][j][1] + x_seq[(size_t)(mb + 1) * DM + n];
            float r2 = acc[i][j][2] + x_seq[(size_t)(mb + 2) * DM + n];
            float r3 = acc[i][j][3] + x_seq[(size_t)(mb + 3) * DM + n];
            *(float4*)(out + (size_t)(b * DM + n) * LL + l0) = make_float4(r0, r1, r2, r3);
        }
    }
}

extern "C" void kernel_launch(void* const* d_in, const int* in_sizes, int n_in,
                              void* d_out, int out_size, void* d_ws, size_t ws_size,
                              hipStream_t stream)
{
    const float* x         = (const float*)d_in[0];
    const float* w_proj    = (const float*)d_in[1];
    const float* ln_g      = (const float*)d_in[2];
    const float* ln_b      = (const float*)d_in[3];
    const float* in_proj_w = (const float*)d_in[4];
    const float* conv_w    = (const float*)d_in[5];
    const float* conv_b    = (const float*)d_in[6];
    const float* x_proj_w  = (const float*)d_in[7];
    const float* dt_proj_w = (const float*)d_in[8];
    const float* dt_proj_b = (const float*)d_in[9];
    const float* A_log     = (const float*)d_in[10];
    const float* Dp        = (const float*)d_in[11];
    const float* out_proj_w= (const float*)d_in[12];
    float* out = (float*)d_out;

    const size_t U = 1048576;
    float* ws    = (float*)d_ws;
    float* x_seq = ws;                 // [0,1)U
    float* xz    = ws + 1 * U;         // [1,5)U
    float* u_buf = ws + 5 * U;         // [5,7)U
    float* x_dbl = ws + 7 * U;         // [7,8)U
    float* delta = ws + 8 * U;         // [8,10)U
    float* y_buf = ws + 10 * U;        // [10,12)U
    float* hend  = ws + 12 * U;        // [12,14)U
    float* decay = ws + 14 * U;        // [14,16)U
    unsigned short* bz      = (unsigned short*)(ws + 16 * U);
    unsigned short* xn_bf   = bz;                 // 1,048,576
    unsigned short* u_bf    = bz + 1048576;       // 2,097,152
    unsigned short* w_in_bf = bz + 3145728;       // 262,144
    unsigned short* w_x_bf  = bz + 3407872;       //  73,728
    unsigned short* w_out_bf= bz + 3481600;       // 131,072

    k_cast_w<<<dim3(1824), dim3(256), 0, stream>>>(
        in_proj_w, x_proj_w, out_proj_w, w_in_bf, w_x_bf, w_out_bf);
    k_proj_ln<<<dim3(MM / 4), dim3(256), 0, stream>>>(x, w_proj, ln_g, ln_b, x_seq, xn_bf);
    k_gemm_bf<<<dim3(32, 8), dim3(256), 0, stream>>>(xn_bf, w_in_bf, xz, 1024, 256, 1024);
    k_conv_silu<<<dim3(Bsz * LL * DI / 256), dim3(256), 0, stream>>>(
        xz, conv_w, conv_b, u_buf, u_bf);
    k_gemm_bf<<<dim3(32, 2), dim3(256), 0, stream>>>(u_bf, w_x_bf, x_dbl, 144, 512, 144);
    k_delta<<<dim3(MM), dim3(256), 0, stream>>>(x_dbl, dt_proj_w, dt_proj_b, delta);
    k_scan_p1<<<dim3(1024), dim3(256), 0, stream>>>(delta, u_buf, x_dbl, A_log, hend, decay);
    k_scan_comb<<<dim3(512), dim3(256), 0, stream>>>(hend, decay);
    k_scan_p2<<<dim3(1024), dim3(256), 0, stream>>>(
        delta, u_buf, x_dbl, A_log, Dp, hend, y_buf);
    k_gemm_out_bf<<<dim3(32, 2), dim3(256), 0, stream>>>(y_buf, xz, w_out_bf, x_seq, out);
}